// Round 5
// baseline (174.661 us; speedup 1.0000x reference)
//
#include <hip/hip_runtime.h>
#include <hip/hip_bf16.h>

// CIN (xDeepFM) fused 3-layer kernel for MI355X — R5: R4's barrierless K-loop
// with the register spill eliminated.
// R4 post-mortem: WRITE_SIZE 1.5->49 MB = scratch spills. LDS was exactly
// 32KB -> 2 WGs/CU fit -> allocator targeted 4 waves/EU (128 VGPR) and
// spilled ~50 regs of a ~175-reg working set to HBM scratch. Fix:
//   (1) LDS bumped to 33.8KB -> only 1 WG/CU fits;
//   (2) amdgpu_waves_per_eu(2,2) pins the allocator to a 256-VGPR budget.
// Everything else identical to R4:
// Layer: h[b,d,h] = sum_f x0[b,f,d] * (S(b,:,d) . W_f)[h] + bias[h]
// Transposed MFMA: D[m=h][n=r=(b,d)] = sum_k W_f[k,h] * S[r,k]
//   A-frag = W, straight global->VGPR (packed bf16, L2-resident),
//            register double-buffered (next step's 8 loads in flight
//            during current step's 16 MFMAs — never drains the queue).
//   B-frag = S, registers, loaded once per layer from LDS state.
//   x0 scale post-MFMA: outacc += xs_lane * Y_f.
// Grid: 256 WGs x 512 thr = 1 WG/CU, 8 waves = 2/SIMD.
// Per-SIMD MFMA issue = 2 x 1152 x 32 cyc = 30.7 us = the dense floor.

typedef __attribute__((ext_vector_type(8))) short short8;
typedef __attribute__((ext_vector_type(8))) __bf16 bf16x8;
typedef __attribute__((ext_vector_type(16))) float f32x16;
typedef __attribute__((ext_vector_type(4))) unsigned short u16x4;

#define DEVINL static __device__ __forceinline__

DEVINL unsigned short f2bf_rne(float f) {
  unsigned int u = __builtin_bit_cast(unsigned int, f);
  unsigned int r = u + 0x7fffu + ((u >> 16) & 1u);
  return (unsigned short)(r >> 16);
}

// MFMA adapter: builtin may want v8i16 or v8bf16. SFINAE both.
template <typename V>
DEVINL auto mfma_32x32x16_bf16(V a, V b, f32x16 c, int)
    -> decltype(__builtin_amdgcn_mfma_f32_32x32x16_bf16(a, b, c, 0, 0, 0)) {
  return __builtin_amdgcn_mfma_f32_32x32x16_bf16(a, b, c, 0, 0, 0);
}
template <typename V>
DEVINL f32x16 mfma_32x32x16_bf16(V a, V b, f32x16 c, long) {
  return __builtin_amdgcn_mfma_f32_32x32x16_bf16(
      __builtin_bit_cast(bf16x8, a), __builtin_bit_cast(bf16x8, b), c, 0, 0, 0);
}
DEVINL f32x16 mfma_bf16(short8 a, short8 b, f32x16 c) {
  return mfma_32x32x16_bf16(a, b, c, 0);
}

// ---------------- W pack kernel (unchanged, verified R2-R4) ----------------
// Packed layout per layer: [f][kb=k>>3][h][j=k&7] bf16 (granule = 1024 u16).
__global__ void pack_w_kernel(const float* __restrict__ W0,
                              const float* __restrict__ W1,
                              const float* __restrict__ W2,
                              unsigned short* __restrict__ Wt) {
  __shared__ float tile[8][132];
  const int u = blockIdx.x;
  const float* W; int FK, f, kb, base;
  if (u < 128)      { W = W0; FK = 32;  f = u >> 2;         kb = u & 3;          base = 0; }
  else if (u < 640) { W = W1; FK = 128; f = (u - 128) >> 4; kb = (u - 128) & 15; base = 131072; }
  else              { W = W2; FK = 128; f = (u - 640) >> 4; kb = (u - 640) & 15; base = 655360; }
  const int t = threadIdx.x;
#pragma unroll
  for (int i = 0; i < 4; ++i) {
    const int e = t + i * 256;  // 0..1023
    const int kk = e >> 7, h = e & 127;
    tile[kk][h] = W[(f * FK + kb * 8 + kk) * 128 + h];
  }
  __syncthreads();
  unsigned short* dst = Wt + base + f * (FK / 8) * 1024 + kb * 1024;
  const int h = t >> 1;
  const int j0 = (t & 1) * 4;
  u16x4 v;
  v.x = f2bf_rne(tile[j0 + 0][h]);
  v.y = f2bf_rne(tile[j0 + 1][h]);
  v.z = f2bf_rne(tile[j0 + 2][h]);
  v.w = f2bf_rne(tile[j0 + 3][h]);
  *(u16x4*)&dst[t * 4] = v;
}

// ---------------- main kernel ----------------
// One "step" = 8 granule loads (16B/lane) + 16 MFMA.
//   layers 1,2 (KQ=8): step s = field f=s; per-lane granule = s*16 + 2*i+half.
//   layer 0   (KQ=2): step s = fields 4s..4s+3; same granule indices
//     (i = 2*fi+kq), only MFMA pairing + xs handling differ.
template <int KQ, int STEPS, int LAYER>
DEVINL void run_layer(const unsigned short* __restrict__ WtL,
                      const float* __restrict__ bias,
                      const float* __restrict__ x0g,
                      float* __restrict__ outp, int outoff,
                      unsigned int* SB,
                      int wgb0, int mrow, int npair, int l31, int half) {
  __syncthreads();  // state in SB ready (prologue or previous epilogue)

  // --- B-frags (S) from SB into registers, once per layer ---
  // slot (half,j) of sfr[nt][kq] holds S[r][k = kq*16 + half*8 + j],
  // r = npair*64 + nt*32 + l31. SB row k2=k/2 packs (k even lo16, k odd hi16);
  // addr = k2*128 + r -> bank r%32 = l31, conflict-free.
  int4 sfr[2][KQ];
  const int rb = npair * 64;
#pragma unroll
  for (int nt = 0; nt < 2; ++nt) {
    const int r = rb + nt * 32 + l31;
#pragma unroll
    for (int kq = 0; kq < KQ; ++kq) {
      const int row0 = kq * 8 + half * 4;
      int4 v;
      v.x = (int)SB[(row0 + 0) * 128 + r];
      v.y = (int)SB[(row0 + 1) * 128 + r];
      v.z = (int)SB[(row0 + 2) * 128 + r];
      v.w = (int)SB[(row0 + 3) * 128 + r];
      sfr[nt][kq] = v;
    }
  }
  __syncthreads();  // all waves hold sfr; SB free for this layer's epilogue

  f32x16 zv;
#pragma unroll
  for (int e = 0; e < 16; ++e) zv[e] = 0.f;
  f32x16 outacc[2] = {zv, zv};

  // per-lane W base: granule = step*16 + 2*i + half; elem offset h*8 u16
  const char* gb = (const char*)WtL +
                   (size_t)(half * 2048 + (mrow * 32 + l31) * 16);
  const int xb0 = (wgb0 + npair * 2 + 0) * 1024 + l31;
  const int xb1 = (wgb0 + npair * 2 + 1) * 1024 + l31;

  auto ldw = [&](short8* wv, int s) {
#pragma unroll
    for (int i = 0; i < 8; ++i)
      wv[i] = *(const short8*)(gb + (size_t)s * 32768 + i * 4096);
  };
  auto doF = [&](const short8* wv, float xs0, float xs1) {  // KQ==8
    f32x16 Y0, Y1;
#pragma unroll
    for (int i = 0; i < 8; ++i) {
      const short8 s0 = __builtin_bit_cast(short8, sfr[0][i % KQ]);
      const short8 s1 = __builtin_bit_cast(short8, sfr[1][i % KQ]);
      Y0 = mfma_bf16(wv[i], s0, i == 0 ? zv : Y0);
      Y1 = mfma_bf16(wv[i], s1, i == 0 ? zv : Y1);
    }
#pragma unroll
    for (int e = 0; e < 16; ++e) {
      outacc[0][e] += xs0 * Y0[e];
      outacc[1][e] += xs1 * Y1[e];
    }
  };
  auto doG = [&](const short8* wv, const float (&xs)[2][4]) {  // KQ==2
    const short8 s00 = __builtin_bit_cast(short8, sfr[0][0]);
    const short8 s01 = __builtin_bit_cast(short8, sfr[0][KQ - 1]);
    const short8 s10 = __builtin_bit_cast(short8, sfr[1][0]);
    const short8 s11 = __builtin_bit_cast(short8, sfr[1][KQ - 1]);
#pragma unroll
    for (int fi = 0; fi < 4; ++fi) {
      f32x16 Y0 = mfma_bf16(wv[2 * fi], s00, zv);
      Y0 = mfma_bf16(wv[2 * fi + 1], s01, Y0);
      f32x16 Y1 = mfma_bf16(wv[2 * fi], s10, zv);
      Y1 = mfma_bf16(wv[2 * fi + 1], s11, Y1);
#pragma unroll
      for (int e = 0; e < 16; ++e) {
        outacc[0][e] += xs[0][fi] * Y0[e];
        outacc[1][e] += xs[1][fi] * Y1[e];
      }
    }
  };

  short8 wa[8], wb[8];
  if constexpr (KQ == 8) {
    ldw(wa, 0);
    float xa0 = x0g[xb0], xa1 = x0g[xb1];
#pragma unroll 1
    for (int s2 = 0; s2 < STEPS / 2; ++s2) {
      const int s = 2 * s2;
      ldw(wb, s + 1);  // in flight while doF(wa) runs
      const float xv0 = x0g[xb0 + (s + 1) * 32];
      const float xv1 = x0g[xb1 + (s + 1) * 32];
      doF(wa, xa0, xa1);
      if (s + 2 < STEPS) {
        ldw(wa, s + 2);
        xa0 = x0g[xb0 + (s + 2) * 32];
        xa1 = x0g[xb1 + (s + 2) * 32];
      }
      doF(wb, xv0, xv1);
    }
  } else {
    ldw(wa, 0);
    float xa[2][4], xv[2][4];
#pragma unroll
    for (int fi = 0; fi < 4; ++fi) {
      xa[0][fi] = x0g[xb0 + fi * 32];
      xa[1][fi] = x0g[xb1 + fi * 32];
    }
#pragma unroll 1
    for (int s2 = 0; s2 < STEPS / 2; ++s2) {
      const int s = 2 * s2;
      ldw(wb, s + 1);
#pragma unroll
      for (int fi = 0; fi < 4; ++fi) {
        xv[0][fi] = x0g[xb0 + ((s + 1) * 4 + fi) * 32];
        xv[1][fi] = x0g[xb1 + ((s + 1) * 4 + fi) * 32];
      }
      doG(wa, xa);
      if (s + 2 < STEPS) {
        ldw(wa, s + 2);
#pragma unroll
        for (int fi = 0; fi < 4; ++fi) {
          xa[0][fi] = x0g[xb0 + ((s + 2) * 4 + fi) * 32];
          xa[1][fi] = x0g[xb1 + ((s + 2) * 4 + fi) * 32];
        }
      }
      doG(wb, xv);
    }
  }

  // --- epilogue ---
  // C/D layout: col = lane&31 = n (r within 32-block);
  //             row = (reg&3)+8*(reg>>2)+4*half = h within 32-block.
  float bv[16];
#pragma unroll
  for (int e = 0; e < 16; ++e)
    bv[e] = bias[mrow * 32 + (e & 3) + 8 * (e >> 2) + 4 * half];

  if constexpr (LAYER < 2) {
    // next state S'[r][h] = bf16(acc+bias), packed [h/2][r] u32 into SB
#pragma unroll
    for (int nt = 0; nt < 2; ++nt) {
      const int r = rb + nt * 32 + l31;
#pragma unroll
      for (int g = 0; g < 4; ++g) {
        const int h2 = mrow * 16 + 4 * g + 2 * half;
        const float v0 = outacc[nt][4 * g + 0] + bv[4 * g + 0];
        const float v1 = outacc[nt][4 * g + 1] + bv[4 * g + 1];
        const float v2 = outacc[nt][4 * g + 2] + bv[4 * g + 2];
        const float v3 = outacc[nt][4 * g + 3] + bv[4 * g + 3];
        SB[h2 * 128 + r] =
            (unsigned)f2bf_rne(v0) | ((unsigned)f2bf_rne(v1) << 16);
        SB[(h2 + 1) * 128 + r] =
            (unsigned)f2bf_rne(v2) | ((unsigned)f2bf_rne(v3) << 16);
      }
    }
  }

  // final output: out[b, outoff+h] = sum_d acc + 32*bias (d = l31 lanes)
#pragma unroll
  for (int nt = 0; nt < 2; ++nt) {
    float sv[16];
#pragma unroll
    for (int e = 0; e < 16; ++e) {
      float v = outacc[nt][e];
      v += __shfl_xor(v, 1);
      v += __shfl_xor(v, 2);
      v += __shfl_xor(v, 4);
      v += __shfl_xor(v, 8);
      v += __shfl_xor(v, 16);
      sv[e] = v + 32.0f * bv[e];
    }
    if (l31 == 0) {
      const int b = npair * 2 + nt;
#pragma unroll
      for (int g = 0; g < 4; ++g) {
        const int h = mrow * 32 + 8 * g + 4 * half;
        float4 o = {sv[4 * g + 0], sv[4 * g + 1], sv[4 * g + 2], sv[4 * g + 3]};
        *(float4*)&outp[b * 384 + outoff + h] = o;
      }
    }
  }
}

__global__ __launch_bounds__(512, 2)
__attribute__((amdgpu_waves_per_eu(2, 2)))  // pin allocator to 256-VGPR budget
void cin_kernel(
    const float* __restrict__ x0g, const unsigned short* __restrict__ Wt,
    const float* __restrict__ b0, const float* __restrict__ b1,
    const float* __restrict__ b2, float* __restrict__ out) {
  // 33.8KB LDS: state (32KB) + dead tail. >32KB on purpose: forces 1 WG/CU so
  // the register allocator can't target 4 waves/EU (R4's spill cause).
  __shared__ unsigned int SB[8448];

  const int t = threadIdx.x;
  const int lane = t & 63;
  const int w = t >> 6;      // 0..7
  const int mrow = w & 3;    // h-tile of 32
  const int npair = w >> 2;  // batch pair (2 batches each)
  const int l31 = lane & 31, half = lane >> 5;
  const int wgb0 = blockIdx.x * 4;  // 4 batches per WG

  // prologue: S1 = bf16(x0^T) -> SB ([g/2][r] u32, r = b_local*32+d)
#pragma unroll
  for (int s = 0; s < 4; ++s) {
    const int i = t + s * 512;  // 0..2047
    const int r = i & 127, g2 = i >> 7;
    const float* p = &x0g[(wgb0 + (r >> 5)) * 1024 + (2 * g2) * 32 + (r & 31)];
    SB[g2 * 128 + r] =
        (unsigned)f2bf_rne(p[0]) | ((unsigned)f2bf_rne(p[32]) << 16);
  }
  // ordering handled by the entry barrier in run_layer

  float* outp = out + (size_t)wgb0 * 384;
  run_layer<2, 8, 0>(Wt, b0, x0g, outp, 0, SB, wgb0, mrow, npair, l31, half);
  run_layer<8, 32, 1>(Wt + 131072, b1, x0g, outp, 128, SB,
                      wgb0, mrow, npair, l31, half);
  run_layer<8, 32, 2>(Wt + 655360, b2, x0g, outp, 256, SB,
                      wgb0, mrow, npair, l31, half);
}

extern "C" void kernel_launch(void* const* d_in, const int* in_sizes, int n_in,
                              void* d_out, int out_size, void* d_ws, size_t ws_size,
                              hipStream_t stream) {
  (void)in_sizes; (void)n_in; (void)out_size; (void)ws_size;
  const float* x0 = (const float*)d_in[0];
  const float* W0 = (const float*)d_in[1];
  const float* W1 = (const float*)d_in[2];
  const float* W2 = (const float*)d_in[3];
  const float* b0 = (const float*)d_in[4];
  const float* b1 = (const float*)d_in[5];
  const float* b2 = (const float*)d_in[6];
  unsigned short* Wt = (unsigned short*)d_ws;  // 2,359,296 B

  pack_w_kernel<<<1152, 256, 0, stream>>>(W0, W1, W2, Wt);
  // 256 WGs x 512 thr = 1 WG/CU (8 waves, 2/SIMD), barrierless K-loop
  cin_kernel<<<256, 512, 0, stream>>>(x0, Wt, b0, b1, b2, (float*)d_out);
}

// Round 6
// 158.652 us; speedup vs baseline: 1.1009x; 1.1009x over previous
//
#include <hip/hip_runtime.h>
#include <hip/hip_bf16.h>

// CIN (xDeepFM) fused 3-layer kernel for MI355X — R6: R4/R5 barrierless
// K-loop with the register working set SHRUNK TO FIT 128 arch VGPRs.
// R4/R5 post-mortem: both spilled ~90 dwords/thread (WRITE_SIZE 48.5 MB,
// VGPR_Count pinned at 128). launch_bounds(512,2) empirically produces a
// 4-waves/EU register target (CUDA min-blocks semantics), and
// amdgpu_waves_per_eu could not override it. Fix: need ~114 arch VGPRs by
// halving the W double-buffer (8-granule steps -> 4-granule quads).
//   per-wave regs: sfr 64 + wa[4]/wb[4] 32 + addr/xs ~18 = ~114 (Y/outacc
//   in AGPRs). Prefetch distance = 1 quad = 8 MFMA = 256 wave-issue cyc,
//   covers ~200 cyc L2-hit latency (2 waves/SIMD also interleave).
// Structure otherwise identical to R5:
// Layer: h[b,d,h] = sum_f x0[b,f,d] * (S(b,:,d) . W_f)[h] + bias[h]
// Transposed MFMA: D[m=h][n=r=(b,d)] = sum_k W_f[k,h] * S[r,k]
//   A-frag = W, straight global->VGPR (packed bf16, L2-resident),
//   B-frag = S, registers, loaded once per layer from 32KB LDS state,
//   x0 scale post-MFMA: outacc += xs_lane * Y_f.
// Grid: 256 WGs x 512 thr = 1 WG/CU, 8 waves = 2/SIMD; 6 barriers total.

typedef __attribute__((ext_vector_type(8))) short short8;
typedef __attribute__((ext_vector_type(8))) __bf16 bf16x8;
typedef __attribute__((ext_vector_type(16))) float f32x16;
typedef __attribute__((ext_vector_type(4))) unsigned short u16x4;

#define DEVINL static __device__ __forceinline__

DEVINL unsigned short f2bf_rne(float f) {
  unsigned int u = __builtin_bit_cast(unsigned int, f);
  unsigned int r = u + 0x7fffu + ((u >> 16) & 1u);
  return (unsigned short)(r >> 16);
}

// MFMA adapter: builtin may want v8i16 or v8bf16. SFINAE both.
template <typename V>
DEVINL auto mfma_32x32x16_bf16(V a, V b, f32x16 c, int)
    -> decltype(__builtin_amdgcn_mfma_f32_32x32x16_bf16(a, b, c, 0, 0, 0)) {
  return __builtin_amdgcn_mfma_f32_32x32x16_bf16(a, b, c, 0, 0, 0);
}
template <typename V>
DEVINL f32x16 mfma_32x32x16_bf16(V a, V b, f32x16 c, long) {
  return __builtin_amdgcn_mfma_f32_32x32x16_bf16(
      __builtin_bit_cast(bf16x8, a), __builtin_bit_cast(bf16x8, b), c, 0, 0, 0);
}
DEVINL f32x16 mfma_bf16(short8 a, short8 b, f32x16 c) {
  return mfma_32x32x16_bf16(a, b, c, 0);
}

// ---------------- W pack kernel (unchanged, verified R2-R5) ----------------
// Packed layout per layer: [f][kb=k>>3][h][j=k&7] bf16 (granule = 1024 u16).
__global__ void pack_w_kernel(const float* __restrict__ W0,
                              const float* __restrict__ W1,
                              const float* __restrict__ W2,
                              unsigned short* __restrict__ Wt) {
  __shared__ float tile[8][132];
  const int u = blockIdx.x;
  const float* W; int FK, f, kb, base;
  if (u < 128)      { W = W0; FK = 32;  f = u >> 2;         kb = u & 3;          base = 0; }
  else if (u < 640) { W = W1; FK = 128; f = (u - 128) >> 4; kb = (u - 128) & 15; base = 131072; }
  else              { W = W2; FK = 128; f = (u - 640) >> 4; kb = (u - 640) & 15; base = 655360; }
  const int t = threadIdx.x;
#pragma unroll
  for (int i = 0; i < 4; ++i) {
    const int e = t + i * 256;  // 0..1023
    const int kk = e >> 7, h = e & 127;
    tile[kk][h] = W[(f * FK + kb * 8 + kk) * 128 + h];
  }
  __syncthreads();
  unsigned short* dst = Wt + base + f * (FK / 8) * 1024 + kb * 1024;
  const int h = t >> 1;
  const int j0 = (t & 1) * 4;
  u16x4 v;
  v.x = f2bf_rne(tile[j0 + 0][h]);
  v.y = f2bf_rne(tile[j0 + 1][h]);
  v.z = f2bf_rne(tile[j0 + 2][h]);
  v.w = f2bf_rne(tile[j0 + 3][h]);
  *(u16x4*)&dst[t * 4] = v;
}

// ---------------- main kernel ----------------
// K-loop unit = "quad": 4 granule loads (16B/lane) + 8 MFMA.
// Step (= 32 K, one field for L1/L2, four fields for L0) = 2 quads.
// Per-lane granule addr: gb + q*16384 + i*4096 bytes (i = 0..3), where gb
// already folds in half*2048 + h*16.
template <int KQ, int STEPS, int LAYER>
DEVINL void run_layer(const unsigned short* __restrict__ WtL,
                      const float* __restrict__ bias,
                      const float* __restrict__ x0g,
                      float* __restrict__ outp, int outoff,
                      unsigned int* SB,
                      int wgb0, int mrow, int npair, int l31, int half) {
  __syncthreads();  // state in SB ready (prologue or previous epilogue)

  // --- B-frags (S) from SB into registers, once per layer ---
  // slot (half,j) of sfr[nt][kq] holds S[r][k = kq*16 + half*8 + j],
  // r = npair*64 + nt*32 + l31. SB row k2=k/2 packs (k even lo16, k odd hi16);
  // addr = k2*128 + r -> bank r%32 = l31, conflict-free.
  int4 sfr[2][KQ];
  const int rb = npair * 64;
#pragma unroll
  for (int nt = 0; nt < 2; ++nt) {
    const int r = rb + nt * 32 + l31;
#pragma unroll
    for (int kq = 0; kq < KQ; ++kq) {
      const int row0 = kq * 8 + half * 4;
      int4 v;
      v.x = (int)SB[(row0 + 0) * 128 + r];
      v.y = (int)SB[(row0 + 1) * 128 + r];
      v.z = (int)SB[(row0 + 2) * 128 + r];
      v.w = (int)SB[(row0 + 3) * 128 + r];
      sfr[nt][kq] = v;
    }
  }
  __syncthreads();  // all waves hold sfr; SB free for this layer's epilogue

  f32x16 zv;
#pragma unroll
  for (int e = 0; e < 16; ++e) zv[e] = 0.f;
  f32x16 outacc[2] = {zv, zv};

  const char* gb = (const char*)WtL +
                   (size_t)(half * 2048 + (mrow * 32 + l31) * 16);
  const int xb0 = (wgb0 + npair * 2 + 0) * 1024 + l31;
  const int xb1 = (wgb0 + npair * 2 + 1) * 1024 + l31;

  auto ldq = [&](short8* wv, int q) {  // 4 granules of quad q
#pragma unroll
    for (int i = 0; i < 4; ++i)
      wv[i] = *(const short8*)(gb + (size_t)q * 16384 + i * 4096);
  };

  short8 wa[4], wb[4];
  constexpr int NQ = STEPS * 2;

  if constexpr (KQ == 8) {
    // L1/L2: quad pair (2q, 2q+1) = one field; Y persists across the pair.
    f32x16 Y0, Y1;
    ldq(wa, 0);
#pragma unroll 1
    for (int q2 = 0; q2 < NQ / 2; ++q2) {
      const int q = 2 * q2;
      ldq(wb, q + 1);
      const float xs0 = x0g[xb0 + q2 * 32];  // x0[b][f=q2][d=l31]
      const float xs1 = x0g[xb1 + q2 * 32];
#pragma unroll
      for (int i = 0; i < 4; ++i) {  // kq 0..3
        const short8 s0 = __builtin_bit_cast(short8, sfr[0][i]);
        const short8 s1 = __builtin_bit_cast(short8, sfr[1][i]);
        Y0 = mfma_bf16(wa[i], s0, i == 0 ? zv : Y0);
        Y1 = mfma_bf16(wa[i], s1, i == 0 ? zv : Y1);
      }
      if (q + 2 < NQ) ldq(wa, q + 2);
#pragma unroll
      for (int i = 0; i < 4; ++i) {  // kq 4..7
        const short8 s0 = __builtin_bit_cast(short8, sfr[0][4 + i]);
        const short8 s1 = __builtin_bit_cast(short8, sfr[1][4 + i]);
        Y0 = mfma_bf16(wb[i], s0, Y0);
        Y1 = mfma_bf16(wb[i], s1, Y1);
      }
#pragma unroll
      for (int e = 0; e < 16; ++e) {
        outacc[0][e] += xs0 * Y0[e];
        outacc[1][e] += xs1 * Y1[e];
      }
    }
  } else {
    // L0 (KQ=2): quad = 2 fields (granule i: field q*2 + (i>>1), kq = i&1).
    const short8 s00 = __builtin_bit_cast(short8, sfr[0][0]);
    const short8 s01 = __builtin_bit_cast(short8, sfr[0][1]);
    const short8 s10 = __builtin_bit_cast(short8, sfr[1][0]);
    const short8 s11 = __builtin_bit_cast(short8, sfr[1][1]);
    auto doQ = [&](const short8* wv, int q) {
#pragma unroll
      for (int fi = 0; fi < 2; ++fi) {
        const int f = q * 2 + fi;
        const float xs0 = x0g[xb0 + f * 32];
        const float xs1 = x0g[xb1 + f * 32];
        f32x16 Y0 = mfma_bf16(wv[2 * fi], s00, zv);
        Y0 = mfma_bf16(wv[2 * fi + 1], s01, Y0);
        f32x16 Y1 = mfma_bf16(wv[2 * fi], s10, zv);
        Y1 = mfma_bf16(wv[2 * fi + 1], s11, Y1);
#pragma unroll
        for (int e = 0; e < 16; ++e) {
          outacc[0][e] += xs0 * Y0[e];
          outacc[1][e] += xs1 * Y1[e];
        }
      }
    };
    ldq(wa, 0);
#pragma unroll 1
    for (int q2 = 0; q2 < NQ / 2; ++q2) {
      const int q = 2 * q2;
      ldq(wb, q + 1);
      doQ(wa, q);
      if (q + 2 < NQ) ldq(wa, q + 2);
      doQ(wb, q + 1);
    }
  }

  // --- epilogue ---
  // C/D layout: col = lane&31 = n (r within 32-block);
  //             row = (reg&3)+8*(reg>>2)+4*half = h within 32-block.
  float bv[16];
#pragma unroll
  for (int e = 0; e < 16; ++e)
    bv[e] = bias[mrow * 32 + (e & 3) + 8 * (e >> 2) + 4 * half];

  if constexpr (LAYER < 2) {
    // next state S'[r][h] = bf16(acc+bias), packed [h/2][r] u32 into SB
#pragma unroll
    for (int nt = 0; nt < 2; ++nt) {
      const int r = rb + nt * 32 + l31;
#pragma unroll
      for (int g = 0; g < 4; ++g) {
        const int h2 = mrow * 16 + 4 * g + 2 * half;
        const float v0 = outacc[nt][4 * g + 0] + bv[4 * g + 0];
        const float v1 = outacc[nt][4 * g + 1] + bv[4 * g + 1];
        const float v2 = outacc[nt][4 * g + 2] + bv[4 * g + 2];
        const float v3 = outacc[nt][4 * g + 3] + bv[4 * g + 3];
        SB[h2 * 128 + r] =
            (unsigned)f2bf_rne(v0) | ((unsigned)f2bf_rne(v1) << 16);
        SB[(h2 + 1) * 128 + r] =
            (unsigned)f2bf_rne(v2) | ((unsigned)f2bf_rne(v3) << 16);
      }
    }
  }

  // final output: out[b, outoff+h] = sum_d acc + 32*bias (d = l31 lanes)
#pragma unroll
  for (int nt = 0; nt < 2; ++nt) {
    float sv[16];
#pragma unroll
    for (int e = 0; e < 16; ++e) {
      float v = outacc[nt][e];
      v += __shfl_xor(v, 1);
      v += __shfl_xor(v, 2);
      v += __shfl_xor(v, 4);
      v += __shfl_xor(v, 8);
      v += __shfl_xor(v, 16);
      sv[e] = v + 32.0f * bv[e];
    }
    if (l31 == 0) {
      const int b = npair * 2 + nt;
#pragma unroll
      for (int g = 0; g < 4; ++g) {
        const int h = mrow * 32 + 8 * g + 4 * half;
        float4 o = {sv[4 * g + 0], sv[4 * g + 1], sv[4 * g + 2], sv[4 * g + 3]};
        *(float4*)&outp[b * 384 + outoff + h] = o;
      }
    }
  }
}

__global__ __launch_bounds__(512, 1) void cin_kernel(
    const float* __restrict__ x0g, const unsigned short* __restrict__ Wt,
    const float* __restrict__ b0, const float* __restrict__ b1,
    const float* __restrict__ b2, float* __restrict__ out) {
  __shared__ unsigned int SB[64 * 128];  // 32KB state only

  const int t = threadIdx.x;
  const int lane = t & 63;
  const int w = t >> 6;      // 0..7
  const int mrow = w & 3;    // h-tile of 32
  const int npair = w >> 2;  // batch pair (2 batches each)
  const int l31 = lane & 31, half = lane >> 5;
  const int wgb0 = blockIdx.x * 4;  // 4 batches per WG

  // prologue: S1 = bf16(x0^T) -> SB ([g/2][r] u32, r = b_local*32+d)
#pragma unroll
  for (int s = 0; s < 4; ++s) {
    const int i = t + s * 512;  // 0..2047
    const int r = i & 127, g2 = i >> 7;
    const float* p = &x0g[(wgb0 + (r >> 5)) * 1024 + (2 * g2) * 32 + (r & 31)];
    SB[g2 * 128 + r] =
        (unsigned)f2bf_rne(p[0]) | ((unsigned)f2bf_rne(p[32]) << 16);
  }
  // ordering handled by the entry barrier in run_layer

  float* outp = out + (size_t)wgb0 * 384;
  run_layer<2, 8, 0>(Wt, b0, x0g, outp, 0, SB, wgb0, mrow, npair, l31, half);
  run_layer<8, 32, 1>(Wt + 131072, b1, x0g, outp, 128, SB,
                      wgb0, mrow, npair, l31, half);
  run_layer<8, 32, 2>(Wt + 655360, b2, x0g, outp, 256, SB,
                      wgb0, mrow, npair, l31, half);
}

extern "C" void kernel_launch(void* const* d_in, const int* in_sizes, int n_in,
                              void* d_out, int out_size, void* d_ws, size_t ws_size,
                              hipStream_t stream) {
  (void)in_sizes; (void)n_in; (void)out_size; (void)ws_size;
  const float* x0 = (const float*)d_in[0];
  const float* W0 = (const float*)d_in[1];
  const float* W1 = (const float*)d_in[2];
  const float* W2 = (const float*)d_in[3];
  const float* b0 = (const float*)d_in[4];
  const float* b1 = (const float*)d_in[5];
  const float* b2 = (const float*)d_in[6];
  unsigned short* Wt = (unsigned short*)d_ws;  // 2,359,296 B

  pack_w_kernel<<<1152, 256, 0, stream>>>(W0, W1, W2, Wt);
  // 256 WGs x 512 thr = 1 WG/CU (8 waves, 2/SIMD), barrierless K-loop
  cin_kernel<<<256, 512, 0, stream>>>(x0, Wt, b0, b1, b2, (float*)d_out);
}

// Round 7
// 154.480 us; speedup vs baseline: 1.1306x; 1.0270x over previous
//
#include <hip/hip_runtime.h>
#include <hip/hip_bf16.h>

// CIN (xDeepFM) fused 3-layer kernel for MI355X — R7: R6 + per-field stall
// elimination in the K-loop.
// R6 post-mortem: spills gone (WRITE 1.5MB, VGPR 112) but MfmaUtil pinned at
// 34% = pure latency-bound at 2 waves/SIMD. Two identified serializations:
//   (1) xs loaded AFTER the W quad loads and consumed by the FMA tail ->
//       tail's s_waitcnt retires up to xs = vmcnt(0) FULL DRAIN every field;
//   (2) W prefetch distance only ~4 MFMA < L2 latency.
// Fix (uses the 80-reg slack of the 256/wave unified file at 2 waves/SIMD):
//   - xs prefetched one whole iteration ahead, always issued BEFORE W loads:
//     tails consume retired values, zero vmcnt wait;
//   - 4 W quad-buffers, 2 fields per iteration: quads issued >=16 MFMA
//     (~512-1024 cyc) before use; waits are vmcnt(8..12), queue never drains.
// Structure otherwise identical to R6 (layout, epilogue, grid 256x512).
// Layer: h[b,d,h] = sum_f x0[b,f,d] * (S(b,:,d) . W_f)[h] + bias[h]
// Transposed MFMA: D[m=h][n=r=(b,d)] = sum_k W_f[k,h] * S[r,k]
//   A = W straight global->VGPR (L2-resident), B = S in registers (per
//   layer from 32KB LDS state), x0 scale post-MFMA.

typedef __attribute__((ext_vector_type(8))) short short8;
typedef __attribute__((ext_vector_type(8))) __bf16 bf16x8;
typedef __attribute__((ext_vector_type(16))) float f32x16;
typedef __attribute__((ext_vector_type(4))) unsigned short u16x4;

#define DEVINL static __device__ __forceinline__

DEVINL unsigned short f2bf_rne(float f) {
  unsigned int u = __builtin_bit_cast(unsigned int, f);
  unsigned int r = u + 0x7fffu + ((u >> 16) & 1u);
  return (unsigned short)(r >> 16);
}

// MFMA adapter: builtin may want v8i16 or v8bf16. SFINAE both.
template <typename V>
DEVINL auto mfma_32x32x16_bf16(V a, V b, f32x16 c, int)
    -> decltype(__builtin_amdgcn_mfma_f32_32x32x16_bf16(a, b, c, 0, 0, 0)) {
  return __builtin_amdgcn_mfma_f32_32x32x16_bf16(a, b, c, 0, 0, 0);
}
template <typename V>
DEVINL f32x16 mfma_32x32x16_bf16(V a, V b, f32x16 c, long) {
  return __builtin_amdgcn_mfma_f32_32x32x16_bf16(
      __builtin_bit_cast(bf16x8, a), __builtin_bit_cast(bf16x8, b), c, 0, 0, 0);
}
DEVINL f32x16 mfma_bf16(short8 a, short8 b, f32x16 c) {
  return mfma_32x32x16_bf16(a, b, c, 0);
}

// ---------------- W pack kernel (unchanged, verified R2-R6) ----------------
// Packed layout per layer: [f][kb=k>>3][h][j=k&7] bf16 (granule = 1024 u16).
__global__ void pack_w_kernel(const float* __restrict__ W0,
                              const float* __restrict__ W1,
                              const float* __restrict__ W2,
                              unsigned short* __restrict__ Wt) {
  __shared__ float tile[8][132];
  const int u = blockIdx.x;
  const float* W; int FK, f, kb, base;
  if (u < 128)      { W = W0; FK = 32;  f = u >> 2;         kb = u & 3;          base = 0; }
  else if (u < 640) { W = W1; FK = 128; f = (u - 128) >> 4; kb = (u - 128) & 15; base = 131072; }
  else              { W = W2; FK = 128; f = (u - 640) >> 4; kb = (u - 640) & 15; base = 655360; }
  const int t = threadIdx.x;
#pragma unroll
  for (int i = 0; i < 4; ++i) {
    const int e = t + i * 256;  // 0..1023
    const int kk = e >> 7, h = e & 127;
    tile[kk][h] = W[(f * FK + kb * 8 + kk) * 128 + h];
  }
  __syncthreads();
  unsigned short* dst = Wt + base + f * (FK / 8) * 1024 + kb * 1024;
  const int h = t >> 1;
  const int j0 = (t & 1) * 4;
  u16x4 v;
  v.x = f2bf_rne(tile[j0 + 0][h]);
  v.y = f2bf_rne(tile[j0 + 1][h]);
  v.z = f2bf_rne(tile[j0 + 2][h]);
  v.w = f2bf_rne(tile[j0 + 3][h]);
  *(u16x4*)&dst[t * 4] = v;
}

// ---------------- main kernel ----------------
// Quad = 4 granule loads (16B/lane) + 8 MFMA worth of A data.
// Per-lane granule addr: gb + q*16384 + i*4096 bytes (i = 0..3).
template <int KQ, int STEPS, int LAYER>
DEVINL void run_layer(const unsigned short* __restrict__ WtL,
                      const float* __restrict__ bias,
                      const float* __restrict__ x0g,
                      float* __restrict__ outp, int outoff,
                      unsigned int* SB,
                      int wgb0, int mrow, int npair, int l31, int half) {
  __syncthreads();  // state in SB ready (prologue or previous epilogue)

  // --- B-frags (S) from SB into registers, once per layer ---
  // slot (half,j) of sfr[nt][kq] holds S[r][k = kq*16 + half*8 + j],
  // r = npair*64 + nt*32 + l31. SB row k2=k/2 packs (k even lo16, k odd hi16);
  // addr = k2*128 + r -> bank r%32 = l31, conflict-free.
  int4 sfr[2][KQ];
  const int rb = npair * 64;
#pragma unroll
  for (int nt = 0; nt < 2; ++nt) {
    const int r = rb + nt * 32 + l31;
#pragma unroll
    for (int kq = 0; kq < KQ; ++kq) {
      const int row0 = kq * 8 + half * 4;
      int4 v;
      v.x = (int)SB[(row0 + 0) * 128 + r];
      v.y = (int)SB[(row0 + 1) * 128 + r];
      v.z = (int)SB[(row0 + 2) * 128 + r];
      v.w = (int)SB[(row0 + 3) * 128 + r];
      sfr[nt][kq] = v;
    }
  }

  f32x16 zv;
#pragma unroll
  for (int e = 0; e < 16; ++e) zv[e] = 0.f;
  f32x16 outacc[2] = {zv, zv};

  const char* gb = (const char*)WtL +
                   (size_t)(half * 2048 + (mrow * 32 + l31) * 16);
  const int xb0 = (wgb0 + npair * 2 + 0) * 1024 + l31;
  const int xb1 = (wgb0 + npair * 2 + 1) * 1024 + l31;

  auto ldq = [&](short8* wv, int q) {  // 4 granules of quad q
#pragma unroll
    for (int i = 0; i < 4; ++i)
      wv[i] = *(const short8*)(gb + (size_t)q * 16384 + i * 4096);
  };

  if constexpr (KQ == 8) {
    // L1/L2: field f = quads (2f, 2f+1); iteration = 2 fields, 4 quad bufs.
    short8 w0[4], w1[4], w2[4], w3[4];
    // preload quads 0,1 and xs for fields 0,1 BEFORE the sync: the barrier's
    // vmcnt drain absorbs the L2 latency once per layer.
    float xc00 = x0g[xb0], xc01 = x0g[xb1];
    float xc10 = x0g[xb0 + 32], xc11 = x0g[xb1 + 32];
    ldq(w0, 0);
    ldq(w1, 1);
    __syncthreads();  // all waves hold sfr; SB free for this layer's epilogue

    auto doFld = [&](const short8* qa, const short8* qb, float xs0, float xs1) {
      f32x16 Y0, Y1;
#pragma unroll
      for (int i = 0; i < 4; ++i) {  // kq 0..3
        const short8 s0 = __builtin_bit_cast(short8, sfr[0][i]);
        const short8 s1 = __builtin_bit_cast(short8, sfr[1][i]);
        Y0 = mfma_bf16(qa[i], s0, i == 0 ? zv : Y0);
        Y1 = mfma_bf16(qa[i], s1, i == 0 ? zv : Y1);
      }
#pragma unroll
      for (int i = 0; i < 4; ++i) {  // kq 4..7
        const short8 s0 = __builtin_bit_cast(short8, sfr[0][4 + i]);
        const short8 s1 = __builtin_bit_cast(short8, sfr[1][4 + i]);
        Y0 = mfma_bf16(qb[i], s0, Y0);
        Y1 = mfma_bf16(qb[i], s1, Y1);
      }
#pragma unroll
      for (int e = 0; e < 16; ++e) {
        outacc[0][e] += xs0 * Y0[e];
        outacc[1][e] += xs1 * Y1[e];
      }
    };

#pragma unroll 1
    for (int it = 0; it < 16; ++it) {
      const int f = 2 * it;
      // xs for next iteration's fields — issued FIRST so this iter's tails
      // never wait on them, and next iter's tails see them retired.
      float xn00 = xc00, xn01 = xc01, xn10 = xc10, xn11 = xc11;
      if (it < 15) {
        xn00 = x0g[xb0 + (f + 2) * 32]; xn01 = x0g[xb1 + (f + 2) * 32];
        xn10 = x0g[xb0 + (f + 3) * 32]; xn11 = x0g[xb1 + (f + 3) * 32];
      }
      ldq(w2, 4 * it + 2);  // field f+1's quads, used 16 MFMA from now
      ldq(w3, 4 * it + 3);
      doFld(w0, w1, xc00, xc01);           // tail uses retired xc
      if (it < 15) {
        ldq(w0, 4 * it + 4);               // next iter's field f+2
        ldq(w1, 4 * it + 5);
      }
      doFld(w2, w3, xc10, xc11);           // vmcnt(8)-style wait, no drain
      xc00 = xn00; xc01 = xn01; xc10 = xn10; xc11 = xn11;
    }
  } else {
    // L0 (KQ=2): quad q = fields (2q, 2q+1); double buffer, xs one quad ahead.
    short8 wa[4], wb[4];
    float xa0 = x0g[xb0], xa1 = x0g[xb1];
    float xa2 = x0g[xb0 + 32], xa3 = x0g[xb1 + 32];
    ldq(wa, 0);
    __syncthreads();

    const short8 s00 = __builtin_bit_cast(short8, sfr[0][0]);
    const short8 s01 = __builtin_bit_cast(short8, sfr[0][1]);
    const short8 s10 = __builtin_bit_cast(short8, sfr[1][0]);
    const short8 s11 = __builtin_bit_cast(short8, sfr[1][1]);
    auto doQ = [&](const short8* wv, float x0a, float x1a, float x0b,
                   float x1b) {
      f32x16 Y0 = mfma_bf16(wv[0], s00, zv);
      Y0 = mfma_bf16(wv[1], s01, Y0);
      f32x16 Y1 = mfma_bf16(wv[0], s10, zv);
      Y1 = mfma_bf16(wv[1], s11, Y1);
#pragma unroll
      for (int e = 0; e < 16; ++e) {
        outacc[0][e] += x0a * Y0[e];
        outacc[1][e] += x1a * Y1[e];
      }
      Y0 = mfma_bf16(wv[2], s00, zv);
      Y0 = mfma_bf16(wv[3], s01, Y0);
      Y1 = mfma_bf16(wv[2], s10, zv);
      Y1 = mfma_bf16(wv[3], s11, Y1);
#pragma unroll
      for (int e = 0; e < 16; ++e) {
        outacc[0][e] += x0b * Y0[e];
        outacc[1][e] += x1b * Y1[e];
      }
    };

#pragma unroll 1
    for (int q2 = 0; q2 < 8; ++q2) {
      const int q = 2 * q2;
      // xs for quad q+1 (fields 2q+2, 2q+3) — before its ldq
      const float xm0 = x0g[xb0 + (2 * q + 2) * 32];
      const float xm1 = x0g[xb1 + (2 * q + 2) * 32];
      const float xm2 = x0g[xb0 + (2 * q + 3) * 32];
      const float xm3 = x0g[xb1 + (2 * q + 3) * 32];
      ldq(wb, q + 1);
      // xs for quad q+2 (next iter's first quad)
      float xn0 = xa0, xn1 = xa1, xn2 = xa2, xn3 = xa3;
      if (q2 < 7) {
        xn0 = x0g[xb0 + (2 * q + 4) * 32];
        xn1 = x0g[xb1 + (2 * q + 4) * 32];
        xn2 = x0g[xb0 + (2 * q + 5) * 32];
        xn3 = x0g[xb1 + (2 * q + 5) * 32];
      }
      doQ(wa, xa0, xa1, xa2, xa3);
      if (q2 < 7) ldq(wa, q + 2);
      doQ(wb, xm0, xm1, xm2, xm3);
      xa0 = xn0; xa1 = xn1; xa2 = xn2; xa3 = xn3;
    }
  }

  // --- epilogue (unchanged from R6) ---
  // C/D layout: col = lane&31 = n (r within 32-block);
  //             row = (reg&3)+8*(reg>>2)+4*half = h within 32-block.
  float bv[16];
#pragma unroll
  for (int e = 0; e < 16; ++e)
    bv[e] = bias[mrow * 32 + (e & 3) + 8 * (e >> 2) + 4 * half];

  if constexpr (LAYER < 2) {
    // next state S'[r][h] = bf16(acc+bias), packed [h/2][r] u32 into SB
#pragma unroll
    for (int nt = 0; nt < 2; ++nt) {
      const int r = rb + nt * 32 + l31;
#pragma unroll
      for (int g = 0; g < 4; ++g) {
        const int h2 = mrow * 16 + 4 * g + 2 * half;
        const float v0 = outacc[nt][4 * g + 0] + bv[4 * g + 0];
        const float v1 = outacc[nt][4 * g + 1] + bv[4 * g + 1];
        const float v2 = outacc[nt][4 * g + 2] + bv[4 * g + 2];
        const float v3 = outacc[nt][4 * g + 3] + bv[4 * g + 3];
        SB[h2 * 128 + r] =
            (unsigned)f2bf_rne(v0) | ((unsigned)f2bf_rne(v1) << 16);
        SB[(h2 + 1) * 128 + r] =
            (unsigned)f2bf_rne(v2) | ((unsigned)f2bf_rne(v3) << 16);
      }
    }
  }

  // final output: out[b, outoff+h] = sum_d acc + 32*bias (d = l31 lanes)
#pragma unroll
  for (int nt = 0; nt < 2; ++nt) {
    float sv[16];
#pragma unroll
    for (int e = 0; e < 16; ++e) {
      float v = outacc[nt][e];
      v += __shfl_xor(v, 1);
      v += __shfl_xor(v, 2);
      v += __shfl_xor(v, 4);
      v += __shfl_xor(v, 8);
      v += __shfl_xor(v, 16);
      sv[e] = v + 32.0f * bv[e];
    }
    if (l31 == 0) {
      const int b = npair * 2 + nt;
#pragma unroll
      for (int g = 0; g < 4; ++g) {
        const int h = mrow * 32 + 8 * g + 4 * half;
        float4 o = {sv[4 * g + 0], sv[4 * g + 1], sv[4 * g + 2], sv[4 * g + 3]};
        *(float4*)&outp[b * 384 + outoff + h] = o;
      }
    }
  }
}

__global__ __launch_bounds__(512, 1) void cin_kernel(
    const float* __restrict__ x0g, const unsigned short* __restrict__ Wt,
    const float* __restrict__ b0, const float* __restrict__ b1,
    const float* __restrict__ b2, float* __restrict__ out) {
  __shared__ unsigned int SB[64 * 128];  // 32KB state only

  const int t = threadIdx.x;
  const int lane = t & 63;
  const int w = t >> 6;      // 0..7
  const int mrow = w & 3;    // h-tile of 32
  const int npair = w >> 2;  // batch pair (2 batches each)
  const int l31 = lane & 31, half = lane >> 5;
  const int wgb0 = blockIdx.x * 4;  // 4 batches per WG

  // prologue: S1 = bf16(x0^T) -> SB ([g/2][r] u32, r = b_local*32+d)
#pragma unroll
  for (int s = 0; s < 4; ++s) {
    const int i = t + s * 512;  // 0..2047
    const int r = i & 127, g2 = i >> 7;
    const float* p = &x0g[(wgb0 + (r >> 5)) * 1024 + (2 * g2) * 32 + (r & 31)];
    SB[g2 * 128 + r] =
        (unsigned)f2bf_rne(p[0]) | ((unsigned)f2bf_rne(p[32]) << 16);
  }
  // ordering handled by the entry barrier in run_layer

  float* outp = out + (size_t)wgb0 * 384;
  run_layer<2, 8, 0>(Wt, b0, x0g, outp, 0, SB, wgb0, mrow, npair, l31, half);
  run_layer<8, 32, 1>(Wt + 131072, b1, x0g, outp, 128, SB,
                      wgb0, mrow, npair, l31, half);
  run_layer<8, 32, 2>(Wt + 655360, b2, x0g, outp, 256, SB,
                      wgb0, mrow, npair, l31, half);
}

extern "C" void kernel_launch(void* const* d_in, const int* in_sizes, int n_in,
                              void* d_out, int out_size, void* d_ws, size_t ws_size,
                              hipStream_t stream) {
  (void)in_sizes; (void)n_in; (void)out_size; (void)ws_size;
  const float* x0 = (const float*)d_in[0];
  const float* W0 = (const float*)d_in[1];
  const float* W1 = (const float*)d_in[2];
  const float* W2 = (const float*)d_in[3];
  const float* b0 = (const float*)d_in[4];
  const float* b1 = (const float*)d_in[5];
  const float* b2 = (const float*)d_in[6];
  unsigned short* Wt = (unsigned short*)d_ws;  // 2,359,296 B

  pack_w_kernel<<<1152, 256, 0, stream>>>(W0, W1, W2, Wt);
  // 256 WGs x 512 thr = 1 WG/CU (8 waves, 2/SIMD), barrierless K-loop
  cin_kernel<<<256, 512, 0, stream>>>(x0, Wt, b0, b1, b2, (float*)d_out);
}